// Round 9
// baseline (172.389 us; speedup 1.0000x reference)
//
#include <hip/hip_runtime.h>
#include <hip/hip_bf16.h>

typedef __bf16 bf16_t;
typedef __bf16 bf16x8 __attribute__((ext_vector_type(8)));
typedef __bf16 bf16x4 __attribute__((ext_vector_type(4)));
typedef float  floatx4 __attribute__((ext_vector_type(4)));

static __device__ __forceinline__ floatx4 mfma16(bf16x8 a, bf16x8 b, floatx4 c) {
  return __builtin_amdgcn_mfma_f32_16x16x32_bf16(a, b, c, 0, 0, 0);
}

// async global->LDS, 16B per lane; LDS dest = wave-uniform base + lane*16.
typedef __attribute__((address_space(3))) void lds_vp;
typedef __attribute__((address_space(1))) void glb_vp;
#define GLDS16(g, l) \
  __builtin_amdgcn_global_load_lds((glb_vp*)(g), (lds_vp*)(l), 16, 0, 0)

// ---------------- fused fp32 -> bf16 convert (x, W_QKV, W_O) ----------------
__global__ void cvt_all_kernel(const float* __restrict__ x,
                               const float* __restrict__ wqkv,
                               const float* __restrict__ wo,
                               bf16_t* __restrict__ xb,
                               bf16_t* __restrict__ wqkvb,
                               bf16_t* __restrict__ wob) {
  int i = blockIdx.x * blockDim.x + threadIdx.x;     // 0..1310719 float4s
  const float4* src; bf16x4* dst; int off;
  if (i < 1048576)      { src = (const float4*)x;    dst = (bf16x4*)xb;    off = i; }
  else if (i < 1245184) { src = (const float4*)wqkv; dst = (bf16x4*)wqkvb; off = i - 1048576; }
  else                  { src = (const float4*)wo;   dst = (bf16x4*)wob;   off = i - 1245184; }
  float4 v = src[off];
  bf16x4 o;
  o[0] = (bf16_t)v.x; o[1] = (bf16_t)v.y; o[2] = (bf16_t)v.z; o[3] = (bf16_t)v.w;
  dst[off] = o;
}

// ---------------- QKV GEMM: C(M,N) = A(M,K) * B(N,K)^T ----------------
// 128x128 tile, BK=64, double-buffered GLDS staging, one barrier per k-iter.
// Epilogue: Q*(0.125*log2e) [bh][t][64]; K [bh][t][64];
// V-blocks (bn>=8): in-LDS 128x128 transpose -> Vt [bh][64][t'] k-interleaved
// (t' = s*8+h2*4+r2 per 32-group) so attn's PV A-fragment is one b128.
__global__ __launch_bounds__(256) void gemm_qkv(
    const bf16_t* __restrict__ A, const bf16_t* __restrict__ B,
    bf16_t* __restrict__ Qo, bf16_t* __restrict__ Ko, bf16_t* __restrict__ Vto)
{
  __shared__ __align__(16) bf16_t As[2][128 * 64];
  __shared__ __align__(16) bf16_t Bs[2][128 * 64];
  const int tid  = threadIdx.x;
  const int lane = tid & 63;
  const int w    = tid >> 6;
  const int quad = lane >> 4;
  const int l15  = lane & 15;
  const int l7   = lane & 7;
  const int wm   = w & 1;
  const int wn   = w >> 1;
  const int K    = 512;

  floatx4 acc[4][4];
  #pragma unroll
  for (int i = 0; i < 4; ++i)
    #pragma unroll
    for (int j = 0; j < 4; ++j)
      acc[i][j] = (floatx4){0.f, 0.f, 0.f, 0.f};

  const bf16_t* Ab = A + (size_t)blockIdx.x * 128 * K;
  const bf16_t* Bb = B + (size_t)blockIdx.y * 128 * K;

  auto stage = [&](int buf, int k0) {
    #pragma unroll
    for (int i = 0; i < 4; ++i) {
      int c = tid + 256 * i;
      int row = c >> 3, colc = c & 7;
      int gofs = ((colc ^ (row & 7)) << 3);
      GLDS16(&Ab[(size_t)row * K + k0 + gofs], &As[buf][c * 8]);
      GLDS16(&Bb[(size_t)row * K + k0 + gofs], &Bs[buf][c * 8]);
    }
  };

  stage(0, 0);
  for (int it = 0; it < 8; ++it) {
    const int cur = it & 1;
    __syncthreads();
    if (it + 1 < 8) stage(cur ^ 1, (it + 1) << 6);
    #pragma unroll
    for (int ks = 0; ks < 2; ++ks) {
      bf16x8 af[4], bfr[4];
      #pragma unroll
      for (int t = 0; t < 4; ++t) {
        af[t]  = *(const bf16x8*)&As[cur][(wm * 64 + t * 16 + l15) * 64 +
                                         (((ks * 4 + quad) ^ l7) << 3)];
        bfr[t] = *(const bf16x8*)&Bs[cur][(wn * 64 + t * 16 + l15) * 64 +
                                         (((ks * 4 + quad) ^ l7) << 3)];
      }
      #pragma unroll
      for (int mt = 0; mt < 4; ++mt)
        #pragma unroll
        for (int nt = 0; nt < 4; ++nt)
          acc[mt][nt] = mfma16(af[mt], bfr[nt], acc[mt][nt]);
    }
  }

  if (blockIdx.y < 8) {
    // ---- Q / K scatter epilogue ----
    #pragma unroll
    for (int mt = 0; mt < 4; ++mt) {
      #pragma unroll
      for (int nt = 0; nt < 4; ++nt) {
        #pragma unroll
        for (int r = 0; r < 4; ++r) {
          int m = blockIdx.x * 128 + wm * 64 + mt * 16 + quad * 4 + r;
          int n = blockIdx.y * 128 + wn * 64 + nt * 16 + l15;
          float v = acc[mt][nt][r];
          int b = m >> 12, t = m & 4095;
          int h = (n >> 6) & 7, d = n & 63;
          size_t bh = (size_t)(b * 8 + h);
          if (n < 512)   // fold 1/sqrt(64) * log2(e) -> softmax in log2 domain
            Qo[bh * 262144 + (size_t)t * 64 + d] = (bf16_t)(v * 0.18033688f);
          else
            Ko[bh * 262144 + (size_t)t * 64 + d] = (bf16_t)v;
        }
      }
    }
  } else {
    // ---- V epilogue: transpose through LDS (As region, 32 KB) ----
    __syncthreads();                       // everyone done reading As/Bs
    bf16_t* L = &As[0][0];                 // [n_local][m swizzled] 128x128
    #pragma unroll
    for (int mt = 0; mt < 4; ++mt)
      #pragma unroll
      for (int nt = 0; nt < 4; ++nt) {
        int n_l = wn * 64 + nt * 16 + l15;
        int mc  = wm * 8 + mt * 2 + (quad >> 1);     // m-chunk of 8
        bf16x4 v4;
        #pragma unroll
        for (int r = 0; r < 4; ++r) v4[r] = (bf16_t)acc[mt][nt][r];
        *(bf16x4*)&L[n_l * 128 + ((mc ^ (n_l & 15)) << 3) + (quad & 1) * 4] = v4;
      }
    __syncthreads();
    const int t0 = (blockIdx.x & 31) * 128;
    const int b  = blockIdx.x >> 5;
    #pragma unroll
    for (int i = 0; i < 8; ++i) {
      int c = tid + 256 * i;               // 0..2047: n_l = c>>4, tc = c&15
      int n_l = c >> 4, tc = c & 15;
      int h = ((blockIdx.y - 8) << 1) | (n_l >> 6);
      int d = n_l & 63;
      size_t bh = (size_t)(b * 8 + h);
      int base0 = (tc >> 2) * 32 + (tc & 3) * 4;
      bf16x4 lo = *(const bf16x4*)&L[n_l * 128 +
                     (((base0 >> 3) ^ (n_l & 15)) << 3) + (base0 & 7)];
      bf16x4 hi = *(const bf16x4*)&L[n_l * 128 +
                     ((((base0 + 16) >> 3) ^ (n_l & 15)) << 3) + (base0 & 7)];
      bf16x8 o;
      #pragma unroll
      for (int e = 0; e < 4; ++e) { o[e] = lo[e]; o[e + 4] = hi[e]; }
      *(bf16x8*)&Vto[bh * 262144 + (size_t)d * 4096 + t0 + tc * 8] = o;
    }
  }
}

// ---------------- output GEMM: out(8192,512) = Ob(8192,512) * Wo(512,512)^T ----
// 64x128 tile -> grid (128,4) = 512 blocks = 2/CU. BK=64 dbuf, LDS 48 KB.
__global__ __launch_bounds__(256) void gemm_out(
    const bf16_t* __restrict__ A, const bf16_t* __restrict__ B,
    float* __restrict__ Cf)
{
  __shared__ __align__(16) bf16_t As[2][64 * 64];
  __shared__ __align__(16) bf16_t Bs[2][128 * 64];
  const int tid  = threadIdx.x;
  const int lane = tid & 63;
  const int w    = tid >> 6;               // 0..3, owns n-range w*32..+32
  const int quad = lane >> 4;
  const int l15  = lane & 15;
  const int l7   = lane & 7;

  floatx4 acc[4][2];
  #pragma unroll
  for (int i = 0; i < 4; ++i)
    #pragma unroll
    for (int j = 0; j < 2; ++j)
      acc[i][j] = (floatx4){0.f, 0.f, 0.f, 0.f};

  const bf16_t* Ab = A + (size_t)blockIdx.x * 64 * 512;
  const bf16_t* Bb = B + (size_t)blockIdx.y * 128 * 512;

  auto stage = [&](int buf, int k0) {
    #pragma unroll
    for (int i = 0; i < 2; ++i) {          // A: 512 chunks
      int c = tid + 256 * i;
      int row = c >> 3, colc = c & 7;
      GLDS16(&Ab[(size_t)row * 512 + k0 + ((colc ^ (row & 7)) << 3)],
             &As[buf][c * 8]);
    }
    #pragma unroll
    for (int i = 0; i < 4; ++i) {          // B: 1024 chunks
      int c = tid + 256 * i;
      int row = c >> 3, colc = c & 7;
      GLDS16(&Bb[(size_t)row * 512 + k0 + ((colc ^ (row & 7)) << 3)],
             &Bs[buf][c * 8]);
    }
  };

  stage(0, 0);
  for (int it = 0; it < 8; ++it) {
    const int cur = it & 1;
    __syncthreads();
    if (it + 1 < 8) stage(cur ^ 1, (it + 1) << 6);
    #pragma unroll
    for (int ks = 0; ks < 2; ++ks) {
      bf16x8 af[4], bfr[2];
      #pragma unroll
      for (int t = 0; t < 4; ++t)
        af[t]  = *(const bf16x8*)&As[cur][(t * 16 + l15) * 64 +
                                         (((ks * 4 + quad) ^ l7) << 3)];
      #pragma unroll
      for (int t = 0; t < 2; ++t)
        bfr[t] = *(const bf16x8*)&Bs[cur][(w * 32 + t * 16 + l15) * 64 +
                                         (((ks * 4 + quad) ^ l7) << 3)];
      #pragma unroll
      for (int mt = 0; mt < 4; ++mt)
        #pragma unroll
        for (int nt = 0; nt < 2; ++nt)
          acc[mt][nt] = mfma16(af[mt], bfr[nt], acc[mt][nt]);
    }
  }

  #pragma unroll
  for (int mt = 0; mt < 4; ++mt)
    #pragma unroll
    for (int nt = 0; nt < 2; ++nt)
      #pragma unroll
      for (int r = 0; r < 4; ++r) {
        int m = blockIdx.x * 64 + mt * 16 + quad * 4 + r;
        int n = blockIdx.y * 128 + w * 32 + nt * 16 + l15;
        Cf[(size_t)m * 512 + n] = acc[mt][nt][r];
      }
}

// ---------------- causal flash attention, 64q x 64k tiles ----------------
// 1024 blocks of 256 threads (4 waves), LDS 32 KB -> 4 blocks/CU, every
// resident wave active every iter (no idle partner group), 4 barrier domains
// per CU desync pipe phases. Under round-robin placement the 4 blocks on one
// CU (ids j, j+32, j+64, j+96 per XCD) have qt = {u, 63-u, 31-u, 32+u} ->
// exactly 130 k-iters per CU. Each XCD sees 2 bh (L2 locality).
// S^T = K Q^T; no-max log2-domain softmax (Q pre-scaled by 0.125*log2e);
// P^T feeds PV directly as B-operand; l via ones-row MFMA; Vt k-interleaved
// global layout -> conflict-free b128 PV A-loads. Dbuf, 1 barrier/iter.
__global__ __launch_bounds__(256, 4) void attn_kernel(
    const bf16_t* __restrict__ Qg, const bf16_t* __restrict__ Kgl,
    const bf16_t* __restrict__ Vtg, bf16_t* __restrict__ Og)
{
  __shared__ __align__(16) bf16_t Ks[2][64 * 64];
  __shared__ __align__(16) bf16_t Vts[2][64 * 64];

  const int tid  = threadIdx.x;
  const int lane = tid & 63;
  const int w    = tid >> 6;               // 0..3
  const int quad = lane >> 4;
  const int l15  = lane & 15;

  const int id = blockIdx.x;               // 0..1023
  const int k8 = id & 7;                   // XCD under round-robin (heuristic)
  const int j  = id >> 3;                  // 0..127
  const int bh = 2 * k8 + (j & 1);         // 2 bh per XCD
  const int jj = j >> 1;                   // 0..63
  const int u  = jj & 15, rr = jj >> 4;
  const int qt = (rr == 0) ? u : (rr == 1) ? 63 - u : (rr == 2) ? 31 - u : 32 + u;
  const size_t bh_off = (size_t)bh * 262144;
  const int b = bh >> 3, h = bh & 7;

  // Q fragment in registers (pre-scaled by 0.125*log2e)
  const int gq = qt * 64 + w * 16 + l15;   // this lane's global q row
  bf16x8 aq0, aq1;
  {
    const bf16_t* Qp = Qg + bh_off + (size_t)gq * 64;
    aq0 = *(const bf16x8*)&Qp[quad * 8];
    aq1 = *(const bf16x8*)&Qp[32 + quad * 8];
  }
  bf16x8 ones;
  #pragma unroll
  for (int i = 0; i < 8; ++i) ones[i] = (bf16_t)1.0f;

  floatx4 acc_o[4], acc_l;
  #pragma unroll
  for (int dt = 0; dt < 4; ++dt) acc_o[dt] = (floatx4){0.f, 0.f, 0.f, 0.f};
  acc_l = (floatx4){0.f, 0.f, 0.f, 0.f};

  auto stage = [&](int buf, int kt) {
    const bf16_t* Kp = Kgl + bh_off + (size_t)kt * 4096;
    const bf16_t* Vp = Vtg + bh_off + (size_t)kt * 64;
    #pragma unroll
    for (int i = 0; i < 2; ++i) {
      int c = tid + 256 * i;               // 0..511
      int row = c >> 3, colc = c & 7;
      GLDS16(&Kp[row * 64 + ((colc ^ (row & 7)) << 3)], &Ks[buf][c * 8]);
    }
    #pragma unroll
    for (int i = 0; i < 2; ++i) {
      int c = tid + 256 * i;
      int row = c >> 3, colc = c & 7;      // row = d, colc = t-chunk
      GLDS16(&Vp[(size_t)row * 4096 + ((colc ^ (row & 7)) << 3)], &Vts[buf][c * 8]);
    }
  };

  stage(0, 0);
  const int nkt = qt + 1;                  // 1..64 iters
  for (int kt = 0; kt < nkt; ++kt) {
    const int cur = kt & 1;
    __syncthreads();                       // cur's loads landed during prev compute
    if (kt + 1 < nkt) stage(cur ^ 1, kt + 1);

    // ---- S^T = K Q^T : rows = k (64), cols = q (16 per wave) ----
    floatx4 s[4];
    #pragma unroll
    for (int nt = 0; nt < 4; ++nt) s[nt] = (floatx4){0.f, 0.f, 0.f, 0.f};
    #pragma unroll
    for (int nt = 0; nt < 4; ++nt) {
      bf16x8 bk0 = *(const bf16x8*)&Ks[cur][(nt * 16 + l15) * 64 +
                                           ((quad ^ (l15 & 7)) << 3)];
      s[nt] = mfma16(bk0, aq0, s[nt]);
    }
    #pragma unroll
    for (int nt = 0; nt < 4; ++nt) {
      bf16x8 bk1 = *(const bf16x8*)&Ks[cur][(nt * 16 + l15) * 64 +
                                           (((4 + quad) ^ (l15 & 7)) << 3)];
      s[nt] = mfma16(bk1, aq1, s[nt]);
    }

    // ---- no-max softmax, log2 domain: P = exp2(s) directly ----
    if (kt == qt) {                        // diagonal tile: mask k > q
      #pragma unroll
      for (int nt = 0; nt < 4; ++nt)
        #pragma unroll
        for (int r = 0; r < 4; ++r)
          if (kt * 64 + nt * 16 + quad * 4 + r > gq) s[nt][r] = -3.0e38f;
    }
    #pragma unroll
    for (int nt = 0; nt < 4; ++nt)
      #pragma unroll
      for (int r = 0; r < 4; ++r)
        s[nt][r] = exp2f(s[nt][r]);

    // ---- PV: O^T += V^T P^T ; l += 1^T P^T ----
    #pragma unroll
    for (int kc = 0; kc < 2; ++kc) {
      bf16x8 pb;
      #pragma unroll
      for (int r = 0; r < 4; ++r) {
        pb[r]     = (bf16_t)s[kc * 2][r];
        pb[r + 4] = (bf16_t)s[kc * 2 + 1][r];
      }
      acc_l = mfma16(ones, pb, acc_l);
      #pragma unroll
      for (int dt = 0; dt < 4; ++dt) {
        int row = dt * 16 + l15;
        bf16x8 av = *(const bf16x8*)&Vts[cur][row * 64 +
                                             (((kc * 4 + quad) ^ (l15 & 7)) << 3)];
        acc_o[dt] = mfma16(av, pb, acc_o[dt]);
      }
    }
  }

  // ---- epilogue: O^T -> LDS transpose (reuse Ks[0]) -> coalesced global ----
  __syncthreads();                         // everyone done with Ks/Vts
  bf16_t* Ot = &Ks[0][0];                  // 8 KB: 64 t-rows x 64 d
  const float rl = 1.0f / acc_l[0];
  const int t_own = w * 16 + l15;          // 0..63
  #pragma unroll
  for (int dt = 0; dt < 4; ++dt) {
    bf16x4 o4;
    #pragma unroll
    for (int r = 0; r < 4; ++r) o4[r] = (bf16_t)(acc_o[dt][r] * rl);
    *(bf16x4*)&Ot[t_own * 64 +
                  (((dt * 2 + (quad >> 1)) ^ (t_own & 7)) << 3) + (quad & 1) * 4] = o4;
  }
  __syncthreads();
  #pragma unroll
  for (int i = 0; i < 2; ++i) {
    int cc = tid + 256 * i;                // 0..511 : 64 t-rows x 8 chunks
    int t = cc >> 3, c = cc & 7;
    bf16x8 o8 = *(const bf16x8*)&Ot[t * 64 + ((c ^ (t & 7)) << 3)];
    int trow = qt * 64 + t;
    *(bf16x8*)&Og[((size_t)b * 4096 + trow) * 512 + h * 64 + c * 8] = o8;
  }
}

// ---------------- launcher ----------------
extern "C" void kernel_launch(void* const* d_in, const int* in_sizes, int n_in,
                              void* d_out, int out_size, void* d_ws, size_t ws_size,
                              hipStream_t stream) {
  const float* x    = (const float*)d_in[0];   // (2,4096,512)
  const float* wqkv = (const float*)d_in[1];   // (1536,512)
  const float* wo   = (const float*)d_in[2];   // (512,512)
  float* out = (float*)d_out;                  // (2,4096,512) fp32

  char* ws = (char*)d_ws;
  bf16_t* xb    = (bf16_t*)(ws);                 //  8 MB (reused as Ob after gemm1)
  bf16_t* wqkvb = (bf16_t*)(ws + 8388608);       //  1.5 MB
  bf16_t* wob   = (bf16_t*)(ws + 9961472);       //  0.5 MB
  bf16_t* Qb    = (bf16_t*)(ws + 10485760);      //  8 MB  [bh][t][64], pre-scaled
  bf16_t* Kb    = (bf16_t*)(ws + 18874368);      //  8 MB  [bh][t][64]
  bf16_t* Vtb   = (bf16_t*)(ws + 27262976);      //  8 MB  [bh][64][t'] k-interleaved
  bf16_t* Ob    = xb;                            //  alias: gemm1 done with xb
  // total 35,651,584 bytes

  cvt_all_kernel<<<5120, 256, 0, stream>>>(x, wqkv, wo, xb, wqkvb, wob);

  gemm_qkv<<<dim3(64, 12), 256, 0, stream>>>(xb, wqkvb, Qb, Kb, Vtb);
  attn_kernel<<<1024, 256, 0, stream>>>(Qb, Kb, Vtb, Ob);
  gemm_out<<<dim3(128, 4), 256, 0, stream>>>(Ob, wob, out);
}